// Round 2
// baseline (135.686 us; speedup 1.0000x reference)
//
#include <hip/hip_runtime.h>
#include <math.h>

#define NVIEW 8
#define CIN   32
#define HF    128
#define WF    128
#define C1    32
#define C2    16
#define C3    8
#define RESO  64
#define PLANE (HF*WF)          // 16384 texels per (v,group) plane, uint4 units

typedef _Float16 half8_t  __attribute__((ext_vector_type(8)));
typedef _Float16 half2_t  __attribute__((ext_vector_type(2)));
typedef float    floatx4  __attribute__((ext_vector_type(4)));

static __device__ __forceinline__ float vox_coord(int idx, float b) {
    const float VOXEL = (float)(0.3 / 64.0);
    const float HALFV = (float)(0.3 / 128.0);
    return (float)idx * VOXEL + HALFV + b;
}

// wave-level LDS sync: each wave uses a private LDS slice; DS ops are in-order
// per wave, so only a lgkmcnt drain + compiler barrier is needed. No s_barrier.
// NOTE: global loads use vmcnt, so prefetches issued BEFORE this in source
// order stay in flight across it — that is the pipeline mechanism below.
static __device__ __forceinline__ void wave_lds_sync() {
    asm volatile("s_waitcnt lgkmcnt(0)" ::: "memory");
}

// ---- K1: G in fp16, planar 8-channel groups: Gh[(v*4+grp)*PLANE + pix] = 16 B
// (8 halves, RTNE). SINGLE-PASS: each thread owns one texel and computes all
// 32 layer-1 outputs (feats read once; it is L3-resident anyway).
// Per-output FMA order over c is unchanged -> bit-identical to prior rounds.
// Block 512 preps mats / fp16 weight frags. ----
__global__ void __launch_bounds__(256) k_g(const float* __restrict__ feats,
                                           const float* __restrict__ W1,
                                           const float* __restrict__ b1,
                                           uint4* __restrict__ Gh,
                                           const float* __restrict__ Ks,
                                           const float* __restrict__ poses,
                                           const int* __restrict__ ihp,
                                           const int* __restrict__ iwp,
                                           const float* __restrict__ W2,
                                           const float* __restrict__ b2,
                                           const float* __restrict__ W3,
                                           const float* __restrict__ b3,
                                           float* __restrict__ mats,
                                           _Float16* __restrict__ w2f,
                                           _Float16* __restrict__ w3f,
                                           float* __restrict__ b2f,
                                           float* __restrict__ b3f) {
    if (blockIdx.x == 512) {
        int t = threadIdx.x;
        if (t < NVIEW * 12) {
            int v = t / 12, rc = t % 12, r = rc / 4, c = rc % 4;
            const float* K = Ks + v * 9;
            const float* P = poses + v * 12;
            float s = K[r*3+0]*P[0*4+c] + K[r*3+1]*P[1*4+c] + K[r*3+2]*P[2*4+c];
            float sc = (r == 0) ? 63.5f / (float)iwp[0]
                     : (r == 1) ? 63.5f / (float)ihp[0] : 1.0f;
            mats[v*12 + r*4 + c] = s * sc;
        }
        if (t < 64) {
            int n = t & 15, g = t >> 4;
            // B-frag for mfma_f32_16x16x32_f16: lane holds B[k=8g+j][n], j=0..7
#pragma unroll
            for (int jj = 0; jj < 8; jj++) {
                int kk = 8 * g + jj;
                w2f[t*8 + jj] = (_Float16)W2[kk * C2 + n];
                float w3v = (kk < C2 && n < C3) ? W3[kk * C3 + n] : 0.0f;  // K,N zero-pad
                w3f[t*8 + jj] = (_Float16)w3v;
            }
            b2f[t] = b2[n];
            b3f[t] = (n < C3) ? b3[n] : 0.0f;
        }
        return;
    }
    // 512 blocks: [view(8)][pixblk(64)] ; thread = one texel, all 32 outputs
    int bx = blockIdx.x;
    int pix = (bx & 63) * 256 + threadIdx.x;   // coalesced
    int v   = bx >> 6;
    const float* fp = feats + ((size_t)v * CIN) * PLANE + pix;
    float g[32];
#pragma unroll
    for (int o = 0; o < C1; o++) g[o] = b1[o];
#pragma unroll
    for (int cc = 0; cc < CIN; cc += 8) {
        float fc[8];
#pragma unroll
        for (int q = 0; q < 8; q++) fc[q] = fp[(size_t)(cc + q) * PLANE];
#pragma unroll
        for (int q = 0; q < 8; q++) {
#pragma unroll
            for (int o = 0; o < C1; o++)
                g[o] = fmaf(fc[q], W1[(cc + q) * C1 + o], g[o]);
        }
    }
#pragma unroll
    for (int grp = 0; grp < 4; grp++) {
        union { half2_t h2[4]; uint4 u; } pk;
#pragma unroll
        for (int q = 0; q < 4; q++) {
            half2_t p = { (_Float16)g[grp*8 + 2*q], (_Float16)g[grp*8 + 2*q + 1] };   // RTNE
            pk.h2[q] = p;
        }
        Gh[((size_t)(v * 4 + grp)) * PLANE + pix] = pk.u;
    }
}

// ---- K2: block = 4 independent waves; each wave = one 64-voxel column.
// Lane (m,g) gathers ONE uint4 (8 fp16 ch) per corner from plane-group g and
// blends with packed v_pk_fma_f16 straight into the MFMA A-frag.
// SOFTWARE PIPELINE (1 view deep): while consuming view v's prefetched data,
// issue view v+1's projection + gathers BEFORE the LDS sync so the loads stay
// in flight (vmcnt) across the LDS-transpose/layer-3 phase. Ballot/popc move
// to issue time (value-identical), double-buffered by view parity.
// All FP op order unchanged -> bit-identical to previous rounds. ----
__global__ void __launch_bounds__(256) k_main(
    const uint4* __restrict__ Gh,
    const float* __restrict__ mats, const float* __restrict__ bbox,
    const _Float16* __restrict__ w2f, const _Float16* __restrict__ w3f,
    const float* __restrict__ b2f, const float* __restrict__ b3f,
    float* __restrict__ out) {
#pragma clang fp contract(fast)
    __shared__ __align__(16) _Float16 h2s[4][64 * 24];   // per-wave [point][ch] slice

    int tid  = threadIdx.x;
    int wv   = tid >> 6;
    int lane = tid & 63;
    int bxs  = (blockIdx.x & 7) * 128 + (blockIdx.x >> 3);  // XCD swizzle (bijective)
    int col  = bxs * 4 + wv;                // 4096 columns: (k<<6)|j
    int j  = col & 63;
    int kz = col >> 6;
    _Float16* h2b = h2s[wv];

    int m = lane & 15, g = lane >> 4;
    float b0 = bbox[0];
    float y = vox_coord(j, bbox[1]);
    float z = vox_coord(kz, bbox[2]);

    half8_t w2frag = *(const half8_t*)(w2f + lane * 8);
    half8_t w3frag = *(const half8_t*)(w3f + lane * 8);
    float b2c = b2f[lane];
    float b3c = b3f[lane];
    floatx4 cb2 = {b2c, b2c, b2c, b2c};
    floatx4 cb3 = {b3c, b3c, b3c, b3c};
    const half2_t z2 = { (_Float16)0.0f, (_Float16)0.0f };

    float M1[16], Msq[16], S16[16];
#pragma unroll
    for (int c = 0; c < 16; c++) { M1[c] = 0.0f; Msq[c] = 0.0f; S16[c] = 0.0f; }

    // ---- pipeline state (all indices compile-time after full unroll) ----
    uint4 gA[4], gB[4], gC[4], gD[4];          // prefetched corners per T-group
    half2_t w4[4][4];                          // packed bilinear weight splats
    unsigned int ball2[2][4];                  // ballot bits, by view parity
    int pcnt2[2];                              // popcount, by view parity
    float vKu, vKv, vKz, vM0, vM4, vM8;        // issue-side view constants
    const uint4* vGv;

    // view constants: same association as reference: M0*x + (M1*y + (M2*z + M3))
#define VSETUP(vv) do {                                                  \
        const float* Mv_ = mats + (vv) * 12;                             \
        vKu = fmaf(Mv_[1], y, fmaf(Mv_[2],  z, Mv_[3]));                 \
        vKv = fmaf(Mv_[5], y, fmaf(Mv_[6],  z, Mv_[7]));                 \
        vKz = fmaf(Mv_[9], y, fmaf(Mv_[10], z, Mv_[11]));                \
        vM0 = Mv_[0]; vM4 = Mv_[4]; vM8 = Mv_[8];                        \
        vGv = Gh + (size_t)((vv) * 4 + g) * PLANE;                       \
    } while (0)

#define ISSUE(T, VPAR) do {                                              \
        int ipt_ = (T) * 16 + m;                                         \
        float x_ = vox_coord(ipt_, b0);                                  \
        float u_  = fmaf(vM0, x_, vKu);                                  \
        float vv_ = fmaf(vM4, x_, vKv);                                  \
        float zc_ = fmaf(vM8, x_, vKz);                                  \
        float invz_ = __builtin_amdgcn_rcpf(zc_);                        \
        float ix_ = u_ * invz_;                                          \
        float iy_ = vv_ * invz_;                                         \
        float fx0_ = floorf(ix_), fy0_ = floorf(iy_);                    \
        float fx1_ = fx0_ + 1.0f, fy1_ = fy0_ + 1.0f;                    \
        bool inb_ = (ix_ >= 0.0f) && (ix_ <= (float)(WF-1)) &&           \
                    (iy_ >= 0.0f) && (iy_ <= (float)(HF-1)) && (zc_ > 0.0f); \
        int cx0_ = (int)fminf(fmaxf(fx0_, 0.0f), (float)(WF-1));         \
        int cx1_ = (int)fminf(fmaxf(fx1_, 0.0f), (float)(WF-1));         \
        int cy0_ = (int)fminf(fmaxf(fy0_, 0.0f), (float)(HF-1));         \
        int cy1_ = (int)fminf(fmaxf(fy1_, 0.0f), (float)(HF-1));         \
        float wnw_ = (fx1_ - ix_) * (fy1_ - iy_);                        \
        float wne_ = (ix_ - fx0_) * (fy1_ - iy_);                        \
        float wsw_ = (fx1_ - ix_) * (iy_ - fy0_);                        \
        float wse_ = (ix_ - fx0_) * (iy_ - fy0_);                        \
        unsigned long long bal_ = __ballot(inb_);                        \
        ball2[VPAR][T] = (unsigned int)bal_;                             \
        pcnt2[VPAR] += __popcll(bal_);                                   \
        int t00_ = cy0_ * WF + cx0_, t01_ = cy0_ * WF + cx1_;            \
        int t10_ = cy1_ * WF + cx0_, t11_ = cy1_ * WF + cx1_;            \
        gA[T] = vGv[t00_]; gB[T] = vGv[t01_];                            \
        gC[T] = vGv[t10_]; gD[T] = vGv[t11_];                            \
        half2_t wnw2_ = { (_Float16)wnw_, (_Float16)wnw_ };   /* RTNE */ \
        half2_t wne2_ = { (_Float16)wne_, (_Float16)wne_ };              \
        half2_t wsw2_ = { (_Float16)wsw_, (_Float16)wsw_ };              \
        half2_t wse2_ = { (_Float16)wse_, (_Float16)wse_ };              \
        w4[T][0] = wnw2_; w4[T][1] = wne2_;                              \
        w4[T][2] = wsw2_; w4[T][3] = wse2_;                              \
    } while (0)

#define CONSUME(T) do {                                                  \
        union { uint4 u; half2_t h[4]; } ua_, ub_, uc_, ud_;             \
        ua_.u = gA[T]; ub_.u = gB[T]; uc_.u = gC[T]; ud_.u = gD[T];      \
        union { half2_t h2[4]; half8_t h8; } r_;                         \
        _Pragma("unroll")                                                \
        for (int c_ = 0; c_ < 4; c_++) {                                 \
            half2_t e_ = ua_.h[c_]*w4[T][0] + ub_.h[c_]*w4[T][1]         \
                       + uc_.h[c_]*w4[T][2] + ud_.h[c_]*w4[T][3];        \
            r_.h2[c_] = __builtin_elementwise_max(e_, z2);  /* relu */   \
        }                                                                \
        c2v[T] = __builtin_amdgcn_mfma_f32_16x16x32_f16(r_.h8, w2frag, cb2, 0, 0, 0); \
    } while (0)

    floatx4 c2v[4];

    // prologue: prefetch all of view 0
    VSETUP(0);
    pcnt2[0] = 0;
    ISSUE(0, 0); ISSUE(1, 0); ISSUE(2, 0); ISSUE(3, 0);

#pragma unroll
    for (int v = 0; v < NVIEW; v++) {
        const int vp = v & 1;
        const int np = (v + 1) & 1;

        // consume view v interleaved with issuing view v+1 (loads go out early,
        // stay in flight across the LDS phase below)
        CONSUME(0);
        if (v < NVIEW - 1) { VSETUP(v + 1); pcnt2[np] = 0; ISSUE(0, np); }
        CONSUME(1);
        if (v < NVIEW - 1) ISSUE(1, np);
        CONSUME(2);
        if (v < NVIEW - 1) ISSUE(2, np);
        CONSUME(3);
        if (v < NVIEW - 1) ISSUE(3, np);

        // relu + cvt in C-layout (lane&15 = out-channel n), store h2 [pt][ch]
        wave_lds_sync();   // guard WAR vs previous view's h2 reads (cheap)
#pragma unroll
        for (int T = 0; T < 4; T++) {
#pragma unroll
            for (int r = 0; r < 4; r++) {
                float vv = fmaxf(c2v[T][r], 0.0f);
                h2b[(T*16 + g*4 + r) * 24 + m] = (_Float16)vv;
            }
        }
        wave_lds_sync();

        // layer 3: A = h2 rows (lane&15 = point-row), B = zero-padded W3, C = bias
        float msr = __builtin_amdgcn_rcpf((float)(pcnt2[vp] >> 2) + 1e-8f);
#pragma unroll
        for (int T = 0; T < 4; T++) {
            half8_t a3 = *(const half8_t*)(h2b + (T*16 + m) * 24 + (g & 1) * 8);
            floatx4 c3 = __builtin_amdgcn_mfma_f32_16x16x32_f16(a3, w3frag, cb3, 0, 0, 0);
#pragma unroll
            for (int r = 0; r < 4; r++) {
                float w = ((ball2[vp][T] >> (g*4 + r)) & 1u) ? msr : 0.0f;
                float val = c3[r];
                float t1 = w * val;
                S16[T*4+r] += w;
                M1[T*4+r]  += t1;
                Msq[T*4+r]  = fmaf(t1, val, Msq[T*4+r]);
            }
        }
    }

#undef VSETUP
#undef ISSUE
#undef CONSUME

    // epilogue: lane (m<8, g) stores points T*16+g*4..+3, mean plane m, var plane m+8
    if (m < C3) {
        size_t base = (size_t)col * 64;
#pragma unroll
        for (int T = 0; T < 4; T++) {
            float4 mn, vr;
            mn.x = M1[T*4+0]; mn.y = M1[T*4+1]; mn.z = M1[T*4+2]; mn.w = M1[T*4+3];
            vr.x = fmaf(mn.x*mn.x, S16[T*4+0]-2.0f, Msq[T*4+0]);
            vr.y = fmaf(mn.y*mn.y, S16[T*4+1]-2.0f, Msq[T*4+1]);
            vr.z = fmaf(mn.z*mn.z, S16[T*4+2]-2.0f, Msq[T*4+2]);
            vr.w = fmaf(mn.w*mn.w, S16[T*4+3]-2.0f, Msq[T*4+3]);
            size_t ob = base + T*16 + g*4;
            *(float4*)(out + (size_t)m       * 262144 + ob) = mn;
            *(float4*)(out + (size_t)(m + 8) * 262144 + ob) = vr;
        }
    }
}

// ---- launch ----
extern "C" void kernel_launch(void* const* d_in, const int* in_sizes, int n_in,
                              void* d_out, int out_size, void* d_ws, size_t ws_size,
                              hipStream_t stream) {
    const float* feats = (const float*)d_in[0];
    const float* poses = (const float*)d_in[1];
    const float* Ks    = (const float*)d_in[2];
    const float* bbox  = (const float*)d_in[3];
    const int*   img_h = (const int*)d_in[4];
    const int*   img_w = (const int*)d_in[5];
    const float* W1    = (const float*)d_in[6];
    const float* b1    = (const float*)d_in[7];
    const float* W2    = (const float*)d_in[8];
    const float* b2    = (const float*)d_in[9];
    const float* W3    = (const float*)d_in[10];
    const float* b3    = (const float*)d_in[11];
    float* out = (float*)d_out;
    float* ws  = (float*)d_ws;

    float*     mats = ws;                        // 96 floats (pad to 128)
    _Float16*  w2f  = (_Float16*)(ws + 128);     // 512 halves (256 floats)
    _Float16*  w3f  = (_Float16*)(ws + 384);     // 512 halves
    float*     b2f  = ws + 640;                  // 64
    float*     b3f  = ws + 704;                  // 64
    uint4*     Gh   = (uint4*)(ws + 768);        // 8*4*16384 uint4 = 8.39 MB, 16B-aligned

    hipLaunchKernelGGL(k_g, dim3(513), dim3(256), 0, stream,
                       feats, W1, b1, Gh, Ks, poses, img_h, img_w,
                       W2, b2, W3, b3, mats, w2f, w3f, b2f, b3f);
    hipLaunchKernelGGL(k_main, dim3(1024), dim3(256), 0, stream,
                       Gh, mats, bbox, w2f, w3f, b2f, b3f, out);
}

// Round 4
// 130.198 us; speedup vs baseline: 1.0421x; 1.0421x over previous
//
#include <hip/hip_runtime.h>
#include <math.h>

#define NVIEW 8
#define CIN   32
#define HF    128
#define WF    128
#define C1    32
#define C2    16
#define C3    8
#define RESO  64
#define PLANE (HF*WF)          // 16384 texels per (v,group) plane, uint4 units

typedef _Float16 half8_t  __attribute__((ext_vector_type(8)));
typedef _Float16 half2_t  __attribute__((ext_vector_type(2)));
typedef float    floatx4  __attribute__((ext_vector_type(4)));

static __device__ __forceinline__ float vox_coord(int idx, float b) {
    const float VOXEL = (float)(0.3 / 64.0);
    const float HALFV = (float)(0.3 / 128.0);
    return (float)idx * VOXEL + HALFV + b;
}

// wave-level LDS sync: each wave uses a private LDS slice; DS ops are in-order
// per wave, so only a lgkmcnt drain + compiler barrier is needed. No s_barrier.
static __device__ __forceinline__ void wave_lds_sync() {
    asm volatile("s_waitcnt lgkmcnt(0)" ::: "memory");
}

// ---- K1: G in fp16, planar 8-channel groups: Gh[(v*4+grp)*PLANE + pix] = 16 B
// (8 halves, RTNE). SINGLE-PASS: each thread owns one texel and computes all
// 32 layer-1 outputs (feats read once; it is L3-resident anyway).
// Per-output FMA order over c is unchanged -> bit-identical to prior rounds.
// Block 512 preps mats / fp16 weight frags. ----
__global__ void __launch_bounds__(256) k_g(const float* __restrict__ feats,
                                           const float* __restrict__ W1,
                                           const float* __restrict__ b1,
                                           uint4* __restrict__ Gh,
                                           const float* __restrict__ Ks,
                                           const float* __restrict__ poses,
                                           const int* __restrict__ ihp,
                                           const int* __restrict__ iwp,
                                           const float* __restrict__ W2,
                                           const float* __restrict__ b2,
                                           const float* __restrict__ W3,
                                           const float* __restrict__ b3,
                                           float* __restrict__ mats,
                                           _Float16* __restrict__ w2f,
                                           _Float16* __restrict__ w3f,
                                           float* __restrict__ b2f,
                                           float* __restrict__ b3f) {
    if (blockIdx.x == 512) {
        int t = threadIdx.x;
        if (t < NVIEW * 12) {
            int v = t / 12, rc = t % 12, r = rc / 4, c = rc % 4;
            const float* K = Ks + v * 9;
            const float* P = poses + v * 12;
            float s = K[r*3+0]*P[0*4+c] + K[r*3+1]*P[1*4+c] + K[r*3+2]*P[2*4+c];
            float sc = (r == 0) ? 63.5f / (float)iwp[0]
                     : (r == 1) ? 63.5f / (float)ihp[0] : 1.0f;
            mats[v*12 + r*4 + c] = s * sc;
        }
        if (t < 64) {
            int n = t & 15, g = t >> 4;
            // B-frag for mfma_f32_16x16x32_f16: lane holds B[k=8g+j][n], j=0..7
#pragma unroll
            for (int jj = 0; jj < 8; jj++) {
                int kk = 8 * g + jj;
                w2f[t*8 + jj] = (_Float16)W2[kk * C2 + n];
                float w3v = (kk < C2 && n < C3) ? W3[kk * C3 + n] : 0.0f;  // K,N zero-pad
                w3f[t*8 + jj] = (_Float16)w3v;
            }
            b2f[t] = b2[n];
            b3f[t] = (n < C3) ? b3[n] : 0.0f;
        }
        return;
    }
    // 512 blocks: [view(8)][pixblk(64)] ; thread = one texel, all 32 outputs
    int bx = blockIdx.x;
    int pix = (bx & 63) * 256 + threadIdx.x;   // coalesced
    int v   = bx >> 6;
    const float* fp = feats + ((size_t)v * CIN) * PLANE + pix;
    float g[32];
#pragma unroll
    for (int o = 0; o < C1; o++) g[o] = b1[o];
#pragma unroll
    for (int cc = 0; cc < CIN; cc += 8) {
        float fc[8];
#pragma unroll
        for (int q = 0; q < 8; q++) fc[q] = fp[(size_t)(cc + q) * PLANE];
#pragma unroll
        for (int q = 0; q < 8; q++) {
#pragma unroll
            for (int o = 0; o < C1; o++)
                g[o] = fmaf(fc[q], W1[(cc + q) * C1 + o], g[o]);
        }
    }
#pragma unroll
    for (int grp = 0; grp < 4; grp++) {
        union { half2_t h2[4]; uint4 u; } pk;
#pragma unroll
        for (int q = 0; q < 4; q++) {
            half2_t p = { (_Float16)g[grp*8 + 2*q], (_Float16)g[grp*8 + 2*q + 1] };   // RTNE
            pk.h2[q] = p;
        }
        Gh[((size_t)(v * 4 + grp)) * PLANE + pix] = pk.u;
    }
}

// ---- K2: block = 4 independent waves; each wave = one 64-voxel column.
// Lane (m,g) gathers ONE uint4 (8 fp16 ch) per corner from plane-group g and
// blends with packed v_pk_fma_f16 straight into the MFMA A-frag.
// Consume-in-place structure (R2's explicit pipeline REGRESSED: holding 16
// uint4 + weight splats across the LDS phase cost VGPR 180 -> 2 waves/SIMD,
// VALUBusy 48%). This round: cap registers via __launch_bounds__(256, 4)
// (min 4 waves/EU -> <=128 VGPR) to double resident waves; TLP hides the
// L2-gather latency instead of a software pipeline. ----
__global__ void __launch_bounds__(256, 4) k_main(
    const uint4* __restrict__ Gh,
    const float* __restrict__ mats, const float* __restrict__ bbox,
    const _Float16* __restrict__ w2f, const _Float16* __restrict__ w3f,
    const float* __restrict__ b2f, const float* __restrict__ b3f,
    float* __restrict__ out) {
#pragma clang fp contract(fast)
    __shared__ __align__(16) _Float16 h2s[4][64 * 24];   // per-wave [point][ch] slice

    int tid  = threadIdx.x;
    int wv   = tid >> 6;
    int lane = tid & 63;
    int bxs  = (blockIdx.x & 7) * 128 + (blockIdx.x >> 3);  // XCD swizzle (bijective)
    int col  = bxs * 4 + wv;               // 4096 columns: (k<<6)|j
    int j  = col & 63;
    int kz = col >> 6;
    _Float16* h2b = h2s[wv];

    int m = lane & 15, g = lane >> 4;
    float y = vox_coord(j, bbox[1]);
    float z = vox_coord(kz, bbox[2]);

    half8_t w2frag = *(const half8_t*)(w2f + lane * 8);
    half8_t w3frag = *(const half8_t*)(w3f + lane * 8);
    float b2c = b2f[lane];
    float b3c = b3f[lane];
    floatx4 cb2 = {b2c, b2c, b2c, b2c};
    floatx4 cb3 = {b3c, b3c, b3c, b3c};
    const half2_t z2 = { (_Float16)0.0f, (_Float16)0.0f };

    float M1[16], Msq[16], S16[16];
#pragma unroll
    for (int c = 0; c < 16; c++) { M1[c] = 0.0f; Msq[c] = 0.0f; S16[c] = 0.0f; }

#pragma unroll 2
    for (int v = 0; v < NVIEW; v++) {
        const float* M = mats + v * 12;
        const uint4* Gv = Gh + (size_t)(v * 4 + g) * PLANE;   // my 8-ch plane group

        // column constants: u = M0*x + Ku  (same association as reference:
        // M0*x + (M1*y + (M2*z + M3)) -> bit-identical to previous rounds)
        float Ku = fmaf(M[1], y, fmaf(M[2],  z, M[3]));
        float Kv = fmaf(M[5], y, fmaf(M[6],  z, M[7]));
        float Kz = fmaf(M[9], y, fmaf(M[10], z, M[11]));
        float M0 = M[0], M4 = M[4], M8 = M[8];

        floatx4 c2v[4];
        unsigned int ballo[4];
        int popc = 0;

#pragma unroll
        for (int T = 0; T < 4; T++) {
            int ipt = T * 16 + m;                      // point index in column
            float x = vox_coord(ipt, bbox[0]);
            float u  = fmaf(M0, x, Ku);
            float vv = fmaf(M4, x, Kv);
            float zc = fmaf(M8, x, Kz);
            float invz = __builtin_amdgcn_rcpf(zc);
            float ix = u * invz;
            float iy = vv * invz;

            float fx0 = floorf(ix), fy0 = floorf(iy);
            float fx1 = fx0 + 1.0f, fy1 = fy0 + 1.0f;
            bool inb = (ix >= 0.0f) && (ix <= (float)(WF-1)) &&
                       (iy >= 0.0f) && (iy <= (float)(HF-1)) && (zc > 0.0f);
            int cx0 = (int)fminf(fmaxf(fx0, 0.0f), (float)(WF-1));
            int cx1 = (int)fminf(fmaxf(fx1, 0.0f), (float)(WF-1));
            int cy0 = (int)fminf(fmaxf(fy0, 0.0f), (float)(HF-1));
            int cy1 = (int)fminf(fmaxf(fy1, 0.0f), (float)(HF-1));
            float wnw = (fx1 - ix) * (fy1 - iy);
            float wne = (ix - fx0) * (fy1 - iy);
            float wsw = (fx1 - ix) * (iy - fy0);
            float wse = (ix - fx0) * (iy - fy0);

            unsigned long long bal = __ballot(inb);    // 4 identical copies per point
            ballo[T] = (unsigned int)bal;              // bits 0..15 = g-group 0
            popc += __popcll(bal);

            int t00 = cy0 * WF + cx0, t01 = cy0 * WF + cx1;
            int t10 = cy1 * WF + cx0, t11 = cy1 * WF + cx1;
            uint4 A = Gv[t00], B = Gv[t01], C = Gv[t10], D = Gv[t11];

            half2_t wnw2 = { (_Float16)wnw, (_Float16)wnw };   // RTNE
            half2_t wne2 = { (_Float16)wne, (_Float16)wne };
            half2_t wsw2 = { (_Float16)wsw, (_Float16)wsw };
            half2_t wse2 = { (_Float16)wse, (_Float16)wse };

            union { uint4 u; half2_t h[4]; } ua, ub, uc, ud;
            ua.u = A; ub.u = B; uc.u = C; ud.u = D;
            union { half2_t h2[4]; half8_t h8; } r;
#pragma unroll
            for (int c = 0; c < 4; c++) {
                half2_t e = ua.h[c]*wnw2 + ub.h[c]*wne2 + uc.h[c]*wsw2 + ud.h[c]*wse2;
                r.h2[c] = __builtin_elementwise_max(e, z2);    // relu, packed
            }

            c2v[T] = __builtin_amdgcn_mfma_f32_16x16x32_f16(r.h8, w2frag, cb2, 0, 0, 0);
        }

        // relu + cvt in C-layout (lane&15 = out-channel n), store h2 [pt][ch]
        wave_lds_sync();   // guard WAR vs previous view's h2 reads (cheap)
#pragma unroll
        for (int T = 0; T < 4; T++) {
#pragma unroll
            for (int r = 0; r < 4; r++) {
                float vv = fmaxf(c2v[T][r], 0.0f);
                h2b[(T*16 + g*4 + r) * 24 + m] = (_Float16)vv;
            }
        }
        wave_lds_sync();

        // layer 3: A = h2 rows (lane&15 = point-row), B = zero-padded W3, C = bias
        float msr = __builtin_amdgcn_rcpf((float)(popc >> 2) + 1e-8f);
#pragma unroll
        for (int T = 0; T < 4; T++) {
            half8_t a3 = *(const half8_t*)(h2b + (T*16 + m) * 24 + (g & 1) * 8);
            floatx4 c3 = __builtin_amdgcn_mfma_f32_16x16x32_f16(a3, w3frag, cb3, 0, 0, 0);
#pragma unroll
            for (int r = 0; r < 4; r++) {
                float w = ((ballo[T] >> (g*4 + r)) & 1u) ? msr : 0.0f;
                float val = c3[r];
                float t1 = w * val;
                S16[T*4+r] += w;
                M1[T*4+r]  += t1;
                Msq[T*4+r]  = fmaf(t1, val, Msq[T*4+r]);
            }
        }
    }

    // epilogue: lane (m<8, g) stores points T*16+g*4..+3, mean plane m, var plane m+8
    if (m < C3) {
        size_t base = (size_t)col * 64;
#pragma unroll
        for (int T = 0; T < 4; T++) {
            float4 mn, vr;
            mn.x = M1[T*4+0]; mn.y = M1[T*4+1]; mn.z = M1[T*4+2]; mn.w = M1[T*4+3];
            vr.x = fmaf(mn.x*mn.x, S16[T*4+0]-2.0f, Msq[T*4+0]);
            vr.y = fmaf(mn.y*mn.y, S16[T*4+1]-2.0f, Msq[T*4+1]);
            vr.z = fmaf(mn.z*mn.z, S16[T*4+2]-2.0f, Msq[T*4+2]);
            vr.w = fmaf(mn.w*mn.w, S16[T*4+3]-2.0f, Msq[T*4+3]);
            size_t ob = base + T*16 + g*4;
            *(float4*)(out + (size_t)m       * 262144 + ob) = mn;
            *(float4*)(out + (size_t)(m + 8) * 262144 + ob) = vr;
        }
    }
}

// ---- launch ----
extern "C" void kernel_launch(void* const* d_in, const int* in_sizes, int n_in,
                              void* d_out, int out_size, void* d_ws, size_t ws_size,
                              hipStream_t stream) {
    const float* feats = (const float*)d_in[0];
    const float* poses = (const float*)d_in[1];
    const float* Ks    = (const float*)d_in[2];
    const float* bbox  = (const float*)d_in[3];
    const int*   img_h = (const int*)d_in[4];
    const int*   img_w = (const int*)d_in[5];
    const float* W1    = (const float*)d_in[6];
    const float* b1    = (const float*)d_in[7];
    const float* W2    = (const float*)d_in[8];
    const float* b2    = (const float*)d_in[9];
    const float* W3    = (const float*)d_in[10];
    const float* b3    = (const float*)d_in[11];
    float* out = (float*)d_out;
    float* ws  = (float*)d_ws;

    float*     mats = ws;                        // 96 floats (pad to 128)
    _Float16*  w2f  = (_Float16*)(ws + 128);     // 512 halves (256 floats)
    _Float16*  w3f  = (_Float16*)(ws + 384);     // 512 halves
    float*     b2f  = ws + 640;                  // 64
    float*     b3f  = ws + 704;                  // 64
    uint4*     Gh   = (uint4*)(ws + 768);        // 8*4*16384 uint4 = 8.39 MB, 16B-aligned

    hipLaunchKernelGGL(k_g, dim3(513), dim3(256), 0, stream,
                       feats, W1, b1, Gh, Ks, poses, img_h, img_w,
                       W2, b2, W3, b3, mats, w2f, w3f, b2f, b3f);
    hipLaunchKernelGGL(k_main, dim3(1024), dim3(256), 0, stream,
                       Gh, mats, bbox, w2f, w3f, b2f, b3f, out);
}